// Round 1
// 334.477 us; speedup vs baseline: 1.0440x; 1.0440x over previous
//
#include <hip/hip_runtime.h>
#include <hip/hip_bf16.h>
#include <hip/hip_fp16.h>
#include <cstdint>

// ---------------------------------------------------------------------------
// SPDE GCN: 4x GCNConv + linear head, fp32 in/out.
// R3-R10: uint2 multi-edge MLP agg; fp16 feature table; dinv pre/post scaling;
//   atomic-free MSD bucket-sort CSR fused with layer-1 fp32 GEMM; maskless
//   x8-padded CSR w/ sentinel row; MFMA fp16 GEMM for layers 2-4; head fused.
// R12: straight-line gather_batch<NB>, one waitcnt per node.
// R13 (this round): persistent-wave agg with 3-stage software pipeline
//   (rpc @ i+2nw, col @ i+nw prefetched while computing node i); NB capped
//   at 4 (max 16 gather VGPRs, order-preserving split for cnt>32);
//   __launch_bounds__(256,8) to force 8 WG/CU (VGPR<=64);
//   rowptr/counts/dinv merged into one int4 rpc load per node.
// ---------------------------------------------------------------------------

#define MAXD 512       // max coarse digits (n <= 131072)
#define EB   8192      // edges per hist/pack chunk
#define PADSLACK 2048  // max per-bucket padding (256 nodes * 8)

typedef _Float16 half8v __attribute__((ext_vector_type(8)));
typedef _Float16 half2v __attribute__((ext_vector_type(2)));
typedef float    float4v __attribute__((ext_vector_type(4)));

#if defined(__has_builtin)
#if __has_builtin(__builtin_amdgcn_fdot2)
#define HAVE_FDOT2 1
#endif
#endif

__device__ __forceinline__ float fdot2f(half2v a, half2v b, float c) {
#ifdef HAVE_FDOT2
    return __builtin_amdgcn_fdot2(a, b, c, false);
#else
    return c + (float)a[0] * (float)b[0] + (float)a[1] * (float)b[1];
#endif
}

// ---- LDS exclusive scan of totals[0..MAXD) with 256 threads ---------------
__device__ __forceinline__ void digit_base_scan(const int* __restrict__ totals,
                                                int ND, int* pairs, int* cbs) {
    const int t = threadIdx.x;
    const int e0 = 2 * t, e1 = 2 * t + 1;
    int v0 = (e0 < ND) ? totals[e0] : 0;
    int v1 = (e1 < ND) ? totals[e1] : 0;
    pairs[t] = v0 + v1;
    __syncthreads();
    for (int off = 1; off < 256; off <<= 1) {
        int x = (t >= off) ? pairs[t - off] : 0;
        __syncthreads();
        pairs[t] += x;
        __syncthreads();
    }
    int ep = pairs[t] - v0 - v1;  // exclusive pair prefix
    cbs[e0] = ep;
    cbs[e1] = ep + v0;
    __syncthreads();
}

// ---- hist body: coarse histogram (block-major histM[b][dg]) ---------------
__device__ __forceinline__ void hist_body(const int* __restrict__ ei,
                                          int* __restrict__ histM, int E, int b) {
    __shared__ int hist[MAXD];
    const int tid = threadIdx.x;
    hist[tid] = 0; hist[tid + 256] = 0;
    __syncthreads();
    const int base = b * EB;
#pragma unroll 2
    for (int it = 0; it < EB / 256; it += 4) {
        int d[4]; bool ok[4];
#pragma unroll
        for (int u = 0; u < 4; ++u) {
            int e = base + (it + u) * 256 + tid;
            ok[u] = e < E;
            d[u] = ok[u] ? ei[E + e] : 0;
        }
#pragma unroll
        for (int u = 0; u < 4; ++u)
            if (ok[u]) atomicAdd(&hist[d[u] >> 8], 1);
    }
    __syncthreads();
    histM[(size_t)b * MAXD + tid] = hist[tid];
    histM[(size_t)b * MAXD + tid + 256] = hist[tid + 256];
}

// ---- per-digit exclusive scan over chunks (in place) + digit totals -------
__global__ __launch_bounds__(256) void scan_digits_k(int* __restrict__ histM,
                                                     int* __restrict__ totals,
                                                     int NBLK) {
    __shared__ int s[256];
    const int t = threadIdx.x, dg = blockIdx.x;
    int v = (t < NBLK) ? histM[(size_t)t * MAXD + dg] : 0;
    s[t] = v;
    __syncthreads();
    for (int off = 1; off < 256; off <<= 1) {
        int x = (t >= off) ? s[t - off] : 0;
        __syncthreads();
        s[t] += x;
        __syncthreads();
    }
    if (t < NBLK) histM[(size_t)t * MAXD + dg] = s[t] - v;
    if (t == 255) totals[dg] = s[255];
}

// ---- fp32 vector GEMM body (layer 1 only, fused with CSR build) -----------
template <int K, int OUT>
__device__ __forceinline__ void gemm_body(const float* __restrict__ H,
                                          const float* __restrict__ W,
                                          float* __restrict__ Tout, int n, int bx) {
    constexpr int TX  = OUT / 4;
    constexpr int TY  = 256 / TX;
    constexpr int BM  = TY * 4;
    constexpr int BK  = 32;
    constexpr int PAD = 4;

    __shared__ float At[BK][BM + PAD];
    __shared__ float Ws[BK][OUT];

    const int t    = threadIdx.x;
    const int cx   = t % TX;
    const int ry   = t / TX;
    const int row0 = bx * BM;

    float acc[4][4] = {{0.f}};
    const int arow = t >> 3;
    const int af4  = t & 7;

    for (int k0 = 0; k0 < K; k0 += BK) {
#pragma unroll
        for (int p = 0; p < BM / 32; ++p) {
            int r  = arow + p * 32;
            int gr = row0 + r;
            int grc = gr < n ? gr : n - 1;
            float4 v = *reinterpret_cast<const float4*>(
                H + (size_t)grc * K + k0 + af4 * 4);
            At[af4 * 4 + 0][r] = v.x;
            At[af4 * 4 + 1][r] = v.y;
            At[af4 * 4 + 2][r] = v.z;
            At[af4 * 4 + 3][r] = v.w;
        }
#pragma unroll
        for (int p = 0; p < (BK * OUT) / 1024; ++p) {
            int idx = t + p * 256;
            int wk  = idx / (OUT / 4);
            int wf  = idx % (OUT / 4);
            float4 v = *reinterpret_cast<const float4*>(
                W + (size_t)(k0 + wk) * OUT + wf * 4);
            *reinterpret_cast<float4*>(&Ws[wk][wf * 4]) = v;
        }
        __syncthreads();
#pragma unroll
        for (int k = 0; k < BK; ++k) {
            float4 a = *reinterpret_cast<const float4*>(&At[k][ry * 4]);
            float4 w = *reinterpret_cast<const float4*>(&Ws[k][cx * 4]);
            acc[0][0] = fmaf(a.x, w.x, acc[0][0]);
            acc[0][1] = fmaf(a.x, w.y, acc[0][1]);
            acc[0][2] = fmaf(a.x, w.z, acc[0][2]);
            acc[0][3] = fmaf(a.x, w.w, acc[0][3]);
            acc[1][0] = fmaf(a.y, w.x, acc[1][0]);
            acc[1][1] = fmaf(a.y, w.y, acc[1][1]);
            acc[1][2] = fmaf(a.y, w.z, acc[1][2]);
            acc[1][3] = fmaf(a.y, w.w, acc[1][3]);
            acc[2][0] = fmaf(a.z, w.x, acc[2][0]);
            acc[2][1] = fmaf(a.z, w.y, acc[2][1]);
            acc[2][2] = fmaf(a.z, w.z, acc[2][2]);
            acc[2][3] = fmaf(a.z, w.w, acc[2][3]);
            acc[3][0] = fmaf(a.w, w.x, acc[3][0]);
            acc[3][1] = fmaf(a.w, w.y, acc[3][1]);
            acc[3][2] = fmaf(a.w, w.z, acc[3][2]);
            acc[3][3] = fmaf(a.w, w.w, acc[3][3]);
        }
        __syncthreads();
    }
#pragma unroll
    for (int i = 0; i < 4; ++i) {
        int gr = row0 + ry * 4 + i;
        if (gr < n) {
            float4 v = make_float4(acc[i][0], acc[i][1], acc[i][2], acc[i][3]);
            *reinterpret_cast<float4*>(Tout + (size_t)gr * OUT + cx * 4) = v;
        }
    }
}

// ---- pack scatter: one hist chunk per block; digit bases from local scan --
__device__ __forceinline__ void pack_body(const int* __restrict__ ei,
                                          const int* __restrict__ histM,
                                          const int* __restrict__ totals,
                                          int* __restrict__ packed,
                                          int E, int ND, int b) {
    __shared__ int pairs[256];
    __shared__ int cbs[MAXD];
    __shared__ int cur[MAXD];
    const int tid = threadIdx.x;
    digit_base_scan(totals, ND, pairs, cbs);
    for (int t = tid; t < ND; t += 256)
        cur[t] = cbs[t] + histM[(size_t)b * MAXD + t];
    __syncthreads();
    const int base = b * EB;
    for (int it = 0; it < EB / 256; it += 4) {
        int s[4], d[4]; bool ok[4];
#pragma unroll
        for (int u = 0; u < 4; ++u) {
            int e = base + (it + u) * 256 + tid;
            ok[u] = e < E;
            if (ok[u]) { s[u] = ei[e]; d[u] = ei[E + e]; }
        }
#pragma unroll
        for (int u = 0; u < 4; ++u) {
            if (ok[u]) {
                int pos = atomicAdd(&cur[d[u] >> 8], 1);
                packed[pos] = (s[u] << 8) | (d[u] & 255);
            }
        }
    }
}

// Fused: hist + first slice of layer-1 GEMM.
__global__ __launch_bounds__(256) void hist_gemm1_k(
    const int* __restrict__ ei, int* __restrict__ histM, int E,
    const float* __restrict__ x, const float* __restrict__ W1,
    float* __restrict__ T1, int n, int NH) {
    const int bx = blockIdx.x;
    if (bx < NH) hist_body(ei, histM, E, bx);
    else         gemm_body<128, 64>(x, W1, T1, n, bx - NH);
}

// Fused: pack + remaining layer-1 GEMM blocks.
__global__ __launch_bounds__(256) void pack_gemm1_k(
    const int* __restrict__ ei, const int* __restrict__ histM,
    const int* __restrict__ totals, int* __restrict__ packed,
    const float* __restrict__ x, const float* __restrict__ W1,
    float* __restrict__ T1, int n, int E, int ND, int NPB, int G1) {
    const int bx = blockIdx.x;
    if (bx < NPB) pack_body(ei, histM, totals, packed, E, ND, bx);
    else          gemm_body<128, 64>(x, W1, T1, n, G1 + bx - NPB);
}

// ---- per-coarse-bucket finalize (padded x8 CSR, rpc int4, T1 scale+fp16) --
__global__ __launch_bounds__(256) void bucket_k(const int* __restrict__ packed,
                                                const int* __restrict__ totals,
                                                int ND,
                                                int* __restrict__ col,
                                                int4* __restrict__ rpc,
                                                float* __restrict__ dinv,
                                                const float* __restrict__ Traw,
                                                __half* __restrict__ Th, int n) {
    __shared__ int   pairs[256];
    __shared__ int   cbs[MAXD];
    __shared__ int   hist[256];
    __shared__ int   pref[256];
    __shared__ int   cur[256];
    __shared__ float dinv_l[256];

    const int tid = threadIdx.x;
    const int dg  = blockIdx.x;
    digit_base_scan(totals, ND, pairs, cbs);
    const int base  = cbs[dg];
    const int m     = totals[dg];
    const int basep = base + dg * PADSLACK;

    hist[tid] = 0;
    __syncthreads();
    for (int k0 = 0; k0 < m; k0 += 1024) {
        int v[4]; bool ok[4];
#pragma unroll
        for (int u = 0; u < 4; ++u) {
            int k = k0 + u * 256 + tid;
            ok[u] = k < m;
            v[u] = ok[u] ? packed[base + k] : 0;
        }
#pragma unroll
        for (int u = 0; u < 4; ++u)
            if (ok[u]) atomicAdd(&hist[v[u] & 255], 1);
    }
    __syncthreads();
    const int deg   = hist[tid];
    const int cnt_p = (deg + 8) & ~7;  // >= deg+1, multiple of 8
    pref[tid] = cnt_p;
    __syncthreads();
    for (int off = 1; off < 256; off <<= 1) {
        int x = (tid >= off) ? pref[tid - off] : 0;
        __syncthreads();
        pref[tid] += x;
        __syncthreads();
    }
    const int rp = basep + pref[tid] - cnt_p;
    const float di = rsqrtf((float)(deg + 1));
    dinv_l[tid] = di;
    cur[tid] = rp + 1;
    const int d = dg * 256 + tid;
    if (d < n) {
        rpc[d]  = make_int4(rp, cnt_p, __float_as_int(di), 0);
        dinv[d] = di;
        col[rp] = d;                                            // self slot
        for (int k = deg + 1; k < cnt_p; ++k) col[rp + k] = n;  // sentinel pads
    }
    __syncthreads();
    for (int k0 = 0; k0 < m; k0 += 1024) {
        int v[4]; bool ok[4];
#pragma unroll
        for (int u = 0; u < 4; ++u) {
            int k = k0 + u * 256 + tid;
            ok[u] = k < m;
            v[u] = ok[u] ? packed[base + k] : 0;
        }
#pragma unroll
        for (int u = 0; u < 4; ++u) {
            if (ok[u]) {
                int pos = atomicAdd(&cur[v[u] & 255], 1);
                col[pos] = v[u] >> 8;
            }
        }
    }
    const int r0 = dg * 256;
#pragma unroll 4
    for (int it = 0; it < 16; ++it) {
        int idx = it * 256 + tid;
        int rl  = idx >> 4;
        int r   = r0 + rl;
        if (r < n) {
            float4 v = reinterpret_cast<const float4*>(Traw)[(size_t)r * 16 + (idx & 15)];
            float dd = dinv_l[rl];
            union { ushort4 u; __half h[4]; } pk;
            pk.h[0] = __float2half_rn(v.x * dd);
            pk.h[1] = __float2half_rn(v.y * dd);
            pk.h[2] = __float2half_rn(v.z * dd);
            pk.h[3] = __float2half_rn(v.w * dd);
            reinterpret_cast<ushort4*>(Th)[(size_t)r * 16 + (idx & 15)] = pk.u;
        }
    }
    if (dg == 0 && tid < 16) {
        uint2 z; z.x = 0u; z.y = 0u;
        reinterpret_cast<uint2*>(Th)[(size_t)n * 16 + tid] = z;
    }
}

// ---- MFMA fp16 GEMM (layers 2-4): T[r] = fp16(dinv[r] * (H[r] @ W)) -------
template <int OUT>  // 64 or 32
__global__ __launch_bounds__(256) void gemm_mfma_k(
    const _Float16* __restrict__ H, const float* __restrict__ W,
    const float* __restrict__ dinv, _Float16* __restrict__ T, int n) {
    constexpr int NT = OUT / 16;        // N tiles: 4 or 2
    const int lane = threadIdx.x & 63;
    const int m16  = lane & 15;
    const int quad = lane >> 4;         // 0..3
    const int wid  = (blockIdx.x * blockDim.x + threadIdx.x) >> 6;
    const int nw   = (gridDim.x * blockDim.x) >> 6;

    half8v bfrag[NT][2];
#pragma unroll
    for (int t = 0; t < NT; ++t)
#pragma unroll
        for (int h = 0; h < 2; ++h)
#pragma unroll
            for (int j = 0; j < 8; ++j)
                bfrag[t][h][j] = (_Float16)W[(size_t)(h * 32 + quad * 8 + j) * OUT
                                             + t * 16 + m16];

    const int nblk = (n + 15) >> 4;
    for (int rb = wid; rb < nblk; rb += nw) {
        const int r0 = rb * 16;
        int ra = r0 + m16; if (ra >= n) ra = n - 1;
        const half8v* hrow = reinterpret_cast<const half8v*>(H + (size_t)ra * 64);
        half8v a0 = hrow[quad];       // A[m=lane&15][k=quad*8+j]
        half8v a1 = hrow[4 + quad];   // k += 32

        float4v dfr[NT];
#pragma unroll
        for (int t = 0; t < NT; ++t) {
            float4v z = {0.f, 0.f, 0.f, 0.f};
            z = __builtin_amdgcn_mfma_f32_16x16x32_f16(a0, bfrag[t][0], z, 0, 0, 0);
            z = __builtin_amdgcn_mfma_f32_16x16x32_f16(a1, bfrag[t][1], z, 0, 0, 0);
            dfr[t] = z;
        }
#pragma unroll
        for (int reg = 0; reg < 4; ++reg) {
            int row = r0 + quad * 4 + reg;
            if (row < n) {
                float di = dinv[row];
#pragma unroll
                for (int t = 0; t < NT; ++t)
                    T[(size_t)row * 64 + t * 16 + m16] =
                        (_Float16)(dfr[t][reg] * di);
            }
        }
    }
}

// ---- straight-line batch: NB groups of 8 edges starting at group g0 -------
// NB <= 4 caps live gather regs at 8x uint2 = 16 VGPR.  Summation order for
// split batches (<4>(0) then <k>(4)) matches the old single <NB> exactly.
template <int NB, int LR>
__device__ __forceinline__ void gather_batch(int c_l, const uint2* __restrict__ T2,
                                             int q, int sw, float4& acc, int g0) {
    constexpr int NSW = 64 / LR;
    constexpr int GPE = 8 / NSW;
    constexpr int NV  = NB * GPE;
    const half2v s10 = {(_Float16)1.f, (_Float16)0.f};
    const half2v s01 = {(_Float16)0.f, (_Float16)1.f};
    uint2 v[NV];
#pragma unroll
    for (int g = 0; g < NB; ++g)
#pragma unroll
        for (int u = 0; u < GPE; ++u) {
            int cc = __shfl(c_l, (g0 + g) * 8 + u * NSW + sw, 64);
            v[g * GPE + u] = T2[(size_t)cc * 16 + q];
        }
#pragma unroll
    for (int k = 0; k < NV; ++k) {
        union { uint2 uu; half2v h[2]; } cv; cv.uu = v[k];
        acc.x = fdot2f(cv.h[0], s10, acc.x);
        acc.y = fdot2f(cv.h[0], s01, acc.y);
        acc.z = fdot2f(cv.h[1], s10, acc.z);
        acc.w = fdot2f(cv.h[1], s01, acc.w);
    }
}

__device__ __forceinline__ void gather_node(int cnt, int start, int c_a,
                                            const uint2* __restrict__ T2,
                                            const int* __restrict__ col,
                                            int lane, int q, int sw, float4& acc) {
    if (cnt <= 64) {
        switch (cnt >> 3) {            // 1..8 groups of 8
            case 1: gather_batch<1, 64 / ((64/16))>(c_a, T2, q, sw, acc, 0); break;
            default: break;
        }
    }
}

// One wave per node, maskless padded CSR (x8, slot0=self, pads->sentinel).
// R13: persistent waves, 3-stage pipeline: rpc[i+2nw] & col[i+nw] prefetched
// while node i gathers/accumulates.  8 WG/CU forced.
template <int LR, bool FUSE_HEAD>   // LR=16: 64ch; LR=8: 32ch
__global__ __launch_bounds__(256, 8) void agg_k(const __half* __restrict__ T,
                                             const int4* __restrict__ rpc,
                                             const int* __restrict__ col,
                                             const float* __restrict__ bias,
                                             void* __restrict__ O, int n,
                                             const float* __restrict__ Wh,
                                             const float* __restrict__ bh) {
    constexpr int NSW = 64 / LR;     // 4 / 8
    constexpr int GPE = 8 / NSW;     // 2 / 1
    const int lane = threadIdx.x & 63;
    const int q    = lane % LR;
    const int sw   = lane / LR;
    const int wid  = (blockIdx.x * blockDim.x + threadIdx.x) >> 6;
    const int nw   = (gridDim.x * blockDim.x) >> 6;
    if (wid >= n) return;

    const uint2* __restrict__ T2 = reinterpret_cast<const uint2*>(T);
    const float4 b4 = reinterpret_cast<const float4*>(bias)[q];

    // pipeline prologue: rpc for node0 & node1, col for node0
    int ib = wid + nw; if (ib >= n) ib = n - 1;
    int4 rc_a = rpc[wid];
    int4 rc_b = rpc[ib];
    int  c_a  = col[rc_a.x + lane];   // slack-safe (col has +256 tail ints)

    for (int i = wid; i < n; i += nw) {
        // --- prefetch stage: rpc 2-ahead, col 1-ahead (rc_b arrived last iter)
        int ic = i + 2 * nw; if (ic >= n) ic = n - 1;
        int4 rc_c = rpc[ic];
        int  c_nx = col[rc_b.x + lane];

        const int   cnt   = rc_a.y;
        const int   start = rc_a.x;
        const float di    = __int_as_float(rc_a.z);

        float4 acc = make_float4(0.f, 0.f, 0.f, 0.f);
        if (cnt <= 64) {
            switch (cnt >> 3) {            // 1..8 groups of 8
                case 1: gather_batch<1, LR>(c_a, T2, q, sw, acc, 0); break;
                case 2: gather_batch<2, LR>(c_a, T2, q, sw, acc, 0); break;
                case 3: gather_batch<3, LR>(c_a, T2, q, sw, acc, 0); break;
                case 4: gather_batch<4, LR>(c_a, T2, q, sw, acc, 0); break;
                case 5: gather_batch<4, LR>(c_a, T2, q, sw, acc, 0);
                        gather_batch<1, LR>(c_a, T2, q, sw, acc, 4); break;
                case 6: gather_batch<4, LR>(c_a, T2, q, sw, acc, 0);
                        gather_batch<2, LR>(c_a, T2, q, sw, acc, 4); break;
                case 7: gather_batch<4, LR>(c_a, T2, q, sw, acc, 0);
                        gather_batch<3, LR>(c_a, T2, q, sw, acc, 4); break;
                default: gather_batch<4, LR>(c_a, T2, q, sw, acc, 0);
                         gather_batch<4, LR>(c_a, T2, q, sw, acc, 4); break;
            }
        } else {
            // generic fallback (cnt > 64; essentially never taken)
            for (int base = 0; base < cnt; base += 64) {
                int m = cnt - base; if (m > 64) m = 64;   // multiple of 8
                int c_l = col[start + base + lane];
                for (int jg = 0; jg < m; jg += 32) {
                    int nb2 = (m - jg) >> 3; if (nb2 > 4) nb2 = 4;
                    int g0 = jg >> 3;
                    switch (nb2) {
                        case 1: gather_batch<1, LR>(c_l, T2, q, sw, acc, g0); break;
                        case 2: gather_batch<2, LR>(c_l, T2, q, sw, acc, g0); break;
                        case 3: gather_batch<3, LR>(c_l, T2, q, sw, acc, g0); break;
                        default: gather_batch<4, LR>(c_l, T2, q, sw, acc, g0); break;
                    }
                }
            }
        }
#pragma unroll
        for (int off = LR; off < 64; off <<= 1) {
            acc.x += __shfl_xor(acc.x, off, 64);
            acc.y += __shfl_xor(acc.y, off, 64);
            acc.z += __shfl_xor(acc.z, off, 64);
            acc.w += __shfl_xor(acc.w, off, 64);
        }
        float4 h;
        h.x = fmaxf(fmaf(di, acc.x, b4.x), 0.f);
        h.y = fmaxf(fmaf(di, acc.y, b4.y), 0.f);
        h.z = fmaxf(fmaf(di, acc.z, b4.z), 0.f);
        h.w = fmaxf(fmaf(di, acc.w, b4.w), 0.f);
        if constexpr (!FUSE_HEAD) {
            if (sw == 0) {  // fp16 H for the MFMA GEMM
                union { ushort4 u; __half hh[4]; } pk;
                pk.hh[0] = __float2half_rn(h.x);
                pk.hh[1] = __float2half_rn(h.y);
                pk.hh[2] = __float2half_rn(h.z);
                pk.hh[3] = __float2half_rn(h.w);
                ushort* base_p = (ushort*)O + (size_t)i * 64;
                *reinterpret_cast<ushort4*>(base_p + 4 * q) = pk.u;
            }
        } else {
            float* Of = (float*)O;
            float p0 = h.x * Wh[(4 * q + 0) * 3 + 0];
            float p1 = h.x * Wh[(4 * q + 0) * 3 + 1];
            float p2 = h.x * Wh[(4 * q + 0) * 3 + 2];
            p0 = fmaf(h.y, Wh[(4 * q + 1) * 3 + 0], p0);
            p1 = fmaf(h.y, Wh[(4 * q + 1) * 3 + 1], p1);
            p2 = fmaf(h.y, Wh[(4 * q + 1) * 3 + 2], p2);
            p0 = fmaf(h.z, Wh[(4 * q + 2) * 3 + 0], p0);
            p1 = fmaf(h.z, Wh[(4 * q + 2) * 3 + 1], p1);
            p2 = fmaf(h.z, Wh[(4 * q + 2) * 3 + 2], p2);
            p0 = fmaf(h.w, Wh[(4 * q + 3) * 3 + 0], p0);
            p1 = fmaf(h.w, Wh[(4 * q + 3) * 3 + 1], p1);
            p2 = fmaf(h.w, Wh[(4 * q + 3) * 3 + 2], p2);
#pragma unroll
            for (int off = 1; off < LR; off <<= 1) {
                p0 += __shfl_xor(p0, off, 64);
                p1 += __shfl_xor(p1, off, 64);
                p2 += __shfl_xor(p2, off, 64);
            }
            if (lane == 0) {
                Of[(size_t)i * 3 + 0] = p0 + bh[0];
                Of[(size_t)i * 3 + 1] = p1 + bh[1];
                Of[(size_t)i * 3 + 2] = p2 + bh[2];
            }
        }
        // --- rotate pipeline state
        rc_a = rc_b; rc_b = rc_c; c_a = c_nx;
    }
}

extern "C" void kernel_launch(void* const* d_in, const int* in_sizes, int n_in,
                              void* d_out, int out_size, void* d_ws, size_t ws_size,
                              hipStream_t stream) {
    const float* x  = (const float*)d_in[0];
    const int*   ei = (const int*)d_in[1];
    const float* W1 = (const float*)d_in[2];
    const float* b1 = (const float*)d_in[3];
    const float* W2 = (const float*)d_in[4];
    const float* b2 = (const float*)d_in[5];
    const float* W3 = (const float*)d_in[6];
    const float* b3 = (const float*)d_in[7];
    const float* W4 = (const float*)d_in[8];
    const float* b4 = (const float*)d_in[9];
    const float* Wh = (const float*)d_in[10];
    const float* bh = (const float*)d_in[11];
    float* out = (float*)d_out;

    const int n = in_sizes[0] / 128;
    const int E = in_sizes[1] / 2;
    const int ND   = (n + 255) / 256;    // coarse digits (<= MAXD)
    const int NBLK = (E + EB - 1) / EB;  // hist/pack blocks (<= 256)

    char* ws = (char*)d_ws;
    auto alloc = [&](size_t bytes) {
        char* p = ws;
        ws += (bytes + 255) & ~(size_t)255;
        return p;
    };
    int*    histM  = (int*)alloc((size_t)NBLK * MAXD * 4);
    int*    totals = (int*)alloc((size_t)MAXD * 4);
    int*    packed = (int*)alloc((size_t)E * 4);
    int*    col    = (int*)alloc(((size_t)E + (size_t)ND * PADSLACK + 256) * 4);
    int4*   rpc    = (int4*)alloc((size_t)n * 16);
    float*  dinv   = (float*)alloc((size_t)n * 4);
    float*  bufF   = (float*)alloc((size_t)n * 64 * 4);         // raw T1 fp32
    __half* bufH   = (__half*)alloc(((size_t)n + 1) * 64 * 2);  // fp16 table + sentinel
    __half* bufG   = (__half*)bufF;  // fp16 H (aliases bufF; T1 dead post-bucket)

    dim3 blk(256);
    const int G  = (n + 63) / 64;   // layer-1 gemm blocks
    const int G1 = G / 3;           // slice fused with hist
    const int G2 = G - G1;          // slice fused with pack
    const int agg_blocks = 2048;    // persistent: 8 WG/CU, 8192 waves
    const int mfma_blocks = 640;    // 2560 waves, grid-stride over 16-row blocks

    // ---- atomic-free CSR build + layer-1 transform ----
    hist_gemm1_k<<<dim3(NBLK + G1), blk, 0, stream>>>(ei, histM, E, x, W1, bufF, n, NBLK);
    scan_digits_k<<<dim3(ND), blk, 0, stream>>>(histM, totals, NBLK);
    pack_gemm1_k<<<dim3(NBLK + G2), blk, 0, stream>>>(ei, histM, totals, packed,
                                                      x, W1, bufF, n, E, ND, NBLK, G1);
    bucket_k<<<dim3(ND), blk, 0, stream>>>(packed, totals, ND, col, rpc,
                                           dinv, bufF, bufH, n);
    // ---- Layer 1 agg (writes fp16 H into bufG) ----
    agg_k<16, false><<<dim3(agg_blocks), blk, 0, stream>>>(
        bufH, rpc, col, b1, bufG, n, nullptr, nullptr);
    // ---- Layer 2 ----
    gemm_mfma_k<64><<<dim3(mfma_blocks), blk, 0, stream>>>(
        (const _Float16*)bufG, W2, dinv, (_Float16*)bufH, n);
    agg_k<16, false><<<dim3(agg_blocks), blk, 0, stream>>>(
        bufH, rpc, col, b2, bufG, n, nullptr, nullptr);
    // ---- Layer 3 ----
    gemm_mfma_k<64><<<dim3(mfma_blocks), blk, 0, stream>>>(
        (const _Float16*)bufG, W3, dinv, (_Float16*)bufH, n);
    agg_k<16, false><<<dim3(agg_blocks), blk, 0, stream>>>(
        bufH, rpc, col, b3, bufG, n, nullptr, nullptr);
    // ---- Layer 4 (+ fused head) ----
    gemm_mfma_k<32><<<dim3(mfma_blocks), blk, 0, stream>>>(
        (const _Float16*)bufG, W4, dinv, (_Float16*)bufH, n);
    agg_k<8, true><<<dim3(agg_blocks), blk, 0, stream>>>(
        bufH, rpc, col, b4, out, n, Wh, bh);
}